// Round 1
// baseline (1602.724 us; speedup 1.0000x reference)
//
#include <hip/hip_runtime.h>
#include <hip/hip_bf16.h>

#define N_NODES 100000
#define D 64
#define N_EDGES 1250000

// ---------------------------------------------------------------------------
// Kernel 1: edge scatter  aggr[dst] += x[src]
// 16 threads per edge, each handles 4 consecutive floats (float4 load).
// unsafeAtomicAdd -> global_atomic_add_f32 (native HW fp32 atomic).
// ---------------------------------------------------------------------------
__global__ __launch_bounds__(256) void scatter_kernel(
    const float* __restrict__ x,
    const int* __restrict__ edge_index,  // [2, E] row-major: [0:E]=src, [E:2E]=dst
    float* __restrict__ aggr,
    int E)
{
    int tid = blockIdx.x * blockDim.x + threadIdx.x;
    int e = tid >> 4;
    if (e >= E) return;
    int lane4 = tid & 15;

    int s = edge_index[e];
    int d = edge_index[E + e];

    const float4 v = ((const float4*)(x + (size_t)s * D))[lane4];
    float* out = aggr + (size_t)d * D + lane4 * 4;

    unsafeAtomicAdd(out + 0, v.x);
    unsafeAtomicAdd(out + 1, v.y);
    unsafeAtomicAdd(out + 2, v.z);
    unsafeAtomicAdd(out + 3, v.w);
}

// ---------------------------------------------------------------------------
// Kernel 2: fused node transform
//   out[i] = tanh( aggr[i] @ W_l + b_l + x[i] @ W_r )
// Block: 256 threads, processes 16 nodes.
//   W_l, W_r staged in LDS (32 KB). A/X rows staged in LDS (padded stride 65).
//   Thread t: node m = t>>4, outputs og..og+3 with og = (t&15)*4.
//   Inner loop: per k -> 2 broadcast b32 reads (A,X) + 2 b128 reads (W rows)
//   + 8 FMAs.
// ---------------------------------------------------------------------------
#define NODES_PER_BLOCK 16

__global__ __launch_bounds__(256) void node_transform_kernel(
    const float* __restrict__ x,
    const float* __restrict__ aggr,
    const float* __restrict__ W_l,   // [64,64] row-major [k][o]
    const float* __restrict__ b_l,   // [64]
    const float* __restrict__ W_r,   // [64,64]
    float* __restrict__ out,
    int N)
{
    __shared__ float sWl[D * D];
    __shared__ float sWr[D * D];
    __shared__ float sA[NODES_PER_BLOCK * 65];
    __shared__ float sX[NODES_PER_BLOCK * 65];

    const int t = threadIdx.x;

    // stage weights
    for (int i = t; i < D * D; i += 256) {
        sWl[i] = W_l[i];
        sWr[i] = W_r[i];
    }

    const int og = (t & 15) * 4;   // output group (4 consecutive outputs)
    const int m  = t >> 4;         // local node index 0..15

    const float4 bias = *(const float4*)(b_l + og);

    long base = (long)blockIdx.x * NODES_PER_BLOCK;

    // stage this block's aggr / x rows
    for (int i = t; i < NODES_PER_BLOCK * D; i += 256) {
        int nm = i >> 6;
        int k  = i & 63;
        long node = base + nm;
        if (node < N) {
            sA[nm * 65 + k] = aggr[node * D + k];
            sX[nm * 65 + k] = x[node * D + k];
        }
    }
    __syncthreads();

    long node = base + m;
    if (node >= N) return;

    float ax = bias.x, ay = bias.y, az = bias.z, aw = bias.w;
    const float* __restrict__ ar = &sA[m * 65];
    const float* __restrict__ xr = &sX[m * 65];

#pragma unroll
    for (int k = 0; k < D; k++) {
        float a  = ar[k];
        float xv = xr[k];
        float4 wl = *(const float4*)&sWl[k * D + og];
        float4 wr = *(const float4*)&sWr[k * D + og];
        ax += a * wl.x + xv * wr.x;
        ay += a * wl.y + xv * wr.y;
        az += a * wl.z + xv * wr.z;
        aw += a * wl.w + xv * wr.w;
    }

    float4 r;
    r.x = tanhf(ax);
    r.y = tanhf(ay);
    r.z = tanhf(az);
    r.w = tanhf(aw);
    *(float4*)(out + node * D + og) = r;
}

extern "C" void kernel_launch(void* const* d_in, const int* in_sizes, int n_in,
                              void* d_out, int out_size, void* d_ws, size_t ws_size,
                              hipStream_t stream) {
    const float* x          = (const float*)d_in[0];
    const int*   edge_index = (const int*)d_in[1];   // int32 (JAX canonicalizes int64)
    const float* W_l        = (const float*)d_in[2];
    const float* b_l        = (const float*)d_in[3];
    const float* W_r        = (const float*)d_in[4];
    float* out = (float*)d_out;

    const int N = N_NODES;
    const int E = N_EDGES;

    float* aggr = (float*)d_ws;  // N*D*4 = 25.6 MB scratch

    // zero the accumulator (harness poisons d_ws before every launch)
    hipMemsetAsync(aggr, 0, (size_t)N * D * sizeof(float), stream);

    // scatter: 16 threads/edge
    {
        long total = (long)E * 16;
        int blocks = (int)((total + 255) / 256);
        scatter_kernel<<<blocks, 256, 0, stream>>>(x, edge_index, aggr, E);
    }

    // fused transform + tanh
    {
        int blocks = (N + NODES_PER_BLOCK - 1) / NODES_PER_BLOCK;  // 6250
        node_transform_kernel<<<blocks, 256, 0, stream>>>(x, aggr, W_l, b_l, W_r, out, N);
    }
}

// Round 2
// 383.674 us; speedup vs baseline: 4.1773x; 4.1773x over previous
//
#include <hip/hip_runtime.h>
#include <hip/hip_bf16.h>

#define N_NODES 100000
#define D 64
#define N_EDGES 1250000

#define N_PAD 100096          // 391 * 256, scan coverage
#define SCAN_BLOCKS 391

// ---------------------------------------------------------------------------
// Kernel: degree histogram   deg[dst[e]] += 1
// ---------------------------------------------------------------------------
__global__ __launch_bounds__(256) void hist_kernel(
    const int* __restrict__ dst, int* __restrict__ deg, int E)
{
    int e = blockIdx.x * 256 + threadIdx.x;
    if (e < E) atomicAdd(&deg[dst[e]], 1);
}

// ---------------------------------------------------------------------------
// Scan level 1: per-256-block exclusive scan of deg -> offsets, block totals
// ---------------------------------------------------------------------------
__global__ __launch_bounds__(256) void scan1_kernel(
    const int* __restrict__ deg, int* __restrict__ offsets,
    int* __restrict__ blockSums)
{
    __shared__ int s[256];
    int t = threadIdx.x;
    int gid = blockIdx.x * 256 + t;
    int v = deg[gid];
    s[t] = v;
    __syncthreads();
#pragma unroll
    for (int off = 1; off < 256; off <<= 1) {
        int u = (t >= off) ? s[t - off] : 0;
        __syncthreads();
        s[t] += u;
        __syncthreads();
    }
    offsets[gid] = s[t] - v;                 // exclusive
    if (t == 255) blockSums[blockIdx.x] = s[t];
}

// ---------------------------------------------------------------------------
// Scan level 2: single block scans the 391 block sums (padded to 512)
// ---------------------------------------------------------------------------
__global__ __launch_bounds__(512) void scan2_kernel(
    const int* __restrict__ blockSums, int* __restrict__ blockScanned)
{
    __shared__ int s[512];
    int t = threadIdx.x;
    int v = (t < SCAN_BLOCKS) ? blockSums[t] : 0;
    s[t] = v;
    __syncthreads();
#pragma unroll
    for (int off = 1; off < 512; off <<= 1) {
        int u = (t >= off) ? s[t - off] : 0;
        __syncthreads();
        s[t] += u;
        __syncthreads();
    }
    blockScanned[t] = s[t] - v;              // exclusive
}

// ---------------------------------------------------------------------------
// Scan level 3: add block prefix
// ---------------------------------------------------------------------------
__global__ __launch_bounds__(256) void scan3_kernel(
    int* __restrict__ offsets, const int* __restrict__ blockScanned)
{
    int gid = blockIdx.x * 256 + threadIdx.x;
    offsets[gid] += blockScanned[blockIdx.x];
}

// ---------------------------------------------------------------------------
// Bucket: place src ids into CSR. deg doubles as the cursor via atomicSub.
// ---------------------------------------------------------------------------
__global__ __launch_bounds__(256) void bucket_kernel(
    const int* __restrict__ src, const int* __restrict__ dst,
    const int* __restrict__ offsets, int* __restrict__ deg,
    int* __restrict__ csr_src, int E)
{
    int e = blockIdx.x * 256 + threadIdx.x;
    if (e >= E) return;
    int d = dst[e];
    int pos = atomicSub(&deg[d], 1) - 1;     // deg -> 0, positions deg-1..0
    csr_src[offsets[d] + pos] = src[e];
}

// ---------------------------------------------------------------------------
// Gather: one wave per node, lane = feature. aggr[n][lane] = sum x[src][lane]
// ---------------------------------------------------------------------------
__global__ __launch_bounds__(256) void gather_kernel(
    const float* __restrict__ x, const int* __restrict__ csr_src,
    const int* __restrict__ offsets, float* __restrict__ aggr, int N)
{
    int wave = blockIdx.x * 4 + (threadIdx.x >> 6);
    int lane = threadIdx.x & 63;
    if (wave >= N) return;
    int beg = offsets[wave];
    int end = offsets[wave + 1];
    float acc = 0.0f;
    for (int i = beg; i < end; i++) {
        int s = csr_src[i];                  // wave-uniform broadcast load
        acc += x[(size_t)s * D + lane];      // 256 B coalesced row read
    }
    aggr[(size_t)wave * D + lane] = acc;
}

// ---------------------------------------------------------------------------
// Transform: out = tanh(aggr @ W_l + b_l + x @ W_r)
// Block: 256 threads, 64 nodes. LDS: W (128x64 = 32 KB), feats (64x132 ~33 KB)
// Thread t: outputs og..og+3 (og=(t&15)*4), nodes ng..ng+3 (ng=(t>>4)*4).
// ---------------------------------------------------------------------------
#define TN 64
#define FSTRIDE 132   // 128 + 4 pad, keeps 16B alignment, 2-way-max conflicts

__global__ __launch_bounds__(256) void transform_kernel(
    const float* __restrict__ x, const float* __restrict__ aggr,
    const float* __restrict__ W_l, const float* __restrict__ b_l,
    const float* __restrict__ W_r, float* __restrict__ out, int N)
{
    __shared__ float sW[128 * 64];       // rows 0..63 = W_l, 64..127 = W_r
    __shared__ float sF[TN * FSTRIDE];   // feats: [0..63]=aggr row, [64..127]=x row

    int t = threadIdx.x;
    for (int i = t; i < 64 * 64; i += 256) {
        sW[i] = W_l[i];
        sW[64 * 64 + i] = W_r[i];
    }

    long base = (long)blockIdx.x * TN;

    for (int i = t; i < TN * 32; i += 256) {   // 64 nodes x 32 float4
        int n = i >> 5;
        int q = i & 31;
        long node = base + n;
        float4 v = make_float4(0.f, 0.f, 0.f, 0.f);
        if (node < N) {
            v = (q < 16) ? ((const float4*)(aggr + node * D))[q]
                         : ((const float4*)(x + node * D))[q - 16];
        }
        *(float4*)&sF[n * FSTRIDE + q * 4] = v;
    }
    __syncthreads();

    const int og = (t & 15) * 4;
    const int ng = (t >> 4) * 4;
    float4 b = *(const float4*)(b_l + og);

    float acc[4][4];
#pragma unroll
    for (int i = 0; i < 4; i++) {
        acc[i][0] = b.x; acc[i][1] = b.y; acc[i][2] = b.z; acc[i][3] = b.w;
    }

#pragma unroll 2
    for (int k = 0; k < 128; k += 4) {
        float4 w[4], a[4];
#pragma unroll
        for (int j = 0; j < 4; j++) w[j] = *(const float4*)&sW[(k + j) * 64 + og];
#pragma unroll
        for (int i = 0; i < 4; i++) a[i] = *(const float4*)&sF[(ng + i) * FSTRIDE + k];
#pragma unroll
        for (int i = 0; i < 4; i++) {
            float av[4] = {a[i].x, a[i].y, a[i].z, a[i].w};
#pragma unroll
            for (int j = 0; j < 4; j++) {
                acc[i][0] += av[j] * w[j].x;
                acc[i][1] += av[j] * w[j].y;
                acc[i][2] += av[j] * w[j].z;
                acc[i][3] += av[j] * w[j].w;
            }
        }
    }

#pragma unroll
    for (int i = 0; i < 4; i++) {
        long node = base + ng + i;
        if (node < N) {
            float4 r;
            r.x = tanhf(acc[i][0]);
            r.y = tanhf(acc[i][1]);
            r.z = tanhf(acc[i][2]);
            r.w = tanhf(acc[i][3]);
            *(float4*)(out + node * D + og) = r;
        }
    }
}

extern "C" void kernel_launch(void* const* d_in, const int* in_sizes, int n_in,
                              void* d_out, int out_size, void* d_ws, size_t ws_size,
                              hipStream_t stream) {
    const float* x   = (const float*)d_in[0];
    const int* ei    = (const int*)d_in[1];   // [2,E] int32
    const float* W_l = (const float*)d_in[2];
    const float* b_l = (const float*)d_in[3];
    const float* W_r = (const float*)d_in[4];
    float* out = (float*)d_out;

    const int N = N_NODES;
    const int E = N_EDGES;
    const int* src = ei;
    const int* dst = ei + E;

    // workspace layout
    char* ws = (char*)d_ws;
    float* aggr        = (float*)(ws);                         // 25,600,000 B
    int*   csr_src     = (int*)(ws + 25600000);                //  5,000,000 B
    int*   deg         = (int*)(ws + 30600000);                //    400,384 B (N_PAD ints)
    int*   offsets     = (int*)(ws + 31000384);                //    400,384 B
    int*   blockSums   = (int*)(ws + 31400768);                //      2,048 B
    int*   blockScanned= (int*)(ws + 31402816);                //      2,048 B

    // zero degree array (covers padded tail)
    hipMemsetAsync(deg, 0, N_PAD * sizeof(int), stream);

    hist_kernel<<<(E + 255) / 256, 256, 0, stream>>>(dst, deg, E);
    scan1_kernel<<<SCAN_BLOCKS, 256, 0, stream>>>(deg, offsets, blockSums);
    scan2_kernel<<<1, 512, 0, stream>>>(blockSums, blockScanned);
    scan3_kernel<<<SCAN_BLOCKS, 256, 0, stream>>>(offsets, blockScanned);
    bucket_kernel<<<(E + 255) / 256, 256, 0, stream>>>(src, dst, offsets, deg, csr_src, E);
    gather_kernel<<<(N + 3) / 4, 256, 0, stream>>>(x, csr_src, offsets, aggr, N);
    transform_kernel<<<(N + TN - 1) / TN, 256, 0, stream>>>(x, aggr, W_l, b_l, W_r, out, N);
}

// Round 4
// 298.273 us; speedup vs baseline: 5.3733x; 1.2863x over previous
//
#include <hip/hip_runtime.h>
#include <hip/hip_bf16.h>
#include <hip/hip_fp16.h>

#define N_NODES 100000
#define D 64
#define N_EDGES 1250000

#define N_PAD 100096          // 391 * 256, scan coverage
#define SCAN_BLOCKS 391

typedef unsigned short ushort_t;

// fp16 (e5m10) pack/unpack — 3 more mantissa bits than bf16; round-3's bf16
// version failed absmax 2.29e-2 vs 2e-2, quantization term shrinks 8x here.
__device__ __forceinline__ ushort_t f2h(float f) {
    return __half_as_ushort(__float2half_rn(f));
}
__device__ __forceinline__ float h2f(ushort_t h) {
    return __half2float(__ushort_as_half(h));
}

// ---------------------------------------------------------------------------
// Pre-transform: y = fp16(x @ W_l), z = fp16(x @ W_r + b_l)
// Aggregation commutes with the linear map: (sum x_j)@W_l = sum (x_j@W_l),
// so the gather sums y rows and the final transform disappears.
// Block: 256 threads, 64 nodes. Thread: 4 nodes x 4 outs, both matrices.
// ---------------------------------------------------------------------------
#define TN 64
#define FS 68   // 64 + 4 pad (keeps float4 alignment: 68*4 B = 272 = 17*16)

__global__ __launch_bounds__(256) void pre_kernel(
    const float* __restrict__ x, const float* __restrict__ W_l,
    const float* __restrict__ b_l, const float* __restrict__ W_r,
    ushort_t* __restrict__ y, ushort_t* __restrict__ z, int N)
{
    __shared__ float sW[2 * 64 * 64];   // [0..4095]=W_l, [4096..8191]=W_r
    __shared__ float sX[TN * FS];

    int t = threadIdx.x;
    for (int i = t; i < 64 * 64; i += 256) {
        sW[i] = W_l[i];
        sW[4096 + i] = W_r[i];
    }

    long base = (long)blockIdx.x * TN;
    for (int i = t; i < TN * 16; i += 256) {   // 64 nodes x 16 float4
        int n = i >> 4, q = i & 15;
        long node = base + n;
        float4 v = make_float4(0.f, 0.f, 0.f, 0.f);
        if (node < N) v = ((const float4*)(x + node * D))[q];
        *(float4*)&sX[n * FS + q * 4] = v;
    }
    __syncthreads();

    const int og = (t & 15) * 4;
    const int ng = (t >> 4) * 4;
    float4 b = *(const float4*)(b_l + og);

    float accL[4][4], accR[4][4];
#pragma unroll
    for (int i = 0; i < 4; i++) {
        accL[i][0] = 0.f; accL[i][1] = 0.f; accL[i][2] = 0.f; accL[i][3] = 0.f;
        accR[i][0] = b.x; accR[i][1] = b.y; accR[i][2] = b.z; accR[i][3] = b.w;
    }

#pragma unroll 2
    for (int k = 0; k < 64; k += 4) {
        float4 wl[4], wr[4], a[4];
#pragma unroll
        for (int j = 0; j < 4; j++) {
            wl[j] = *(const float4*)&sW[(k + j) * 64 + og];
            wr[j] = *(const float4*)&sW[4096 + (k + j) * 64 + og];
        }
#pragma unroll
        for (int i = 0; i < 4; i++) a[i] = *(const float4*)&sX[(ng + i) * FS + k];
#pragma unroll
        for (int i = 0; i < 4; i++) {
            float av[4] = {a[i].x, a[i].y, a[i].z, a[i].w};
#pragma unroll
            for (int j = 0; j < 4; j++) {
                accL[i][0] += av[j] * wl[j].x;
                accL[i][1] += av[j] * wl[j].y;
                accL[i][2] += av[j] * wl[j].z;
                accL[i][3] += av[j] * wl[j].w;
                accR[i][0] += av[j] * wr[j].x;
                accR[i][1] += av[j] * wr[j].y;
                accR[i][2] += av[j] * wr[j].z;
                accR[i][3] += av[j] * wr[j].w;
            }
        }
    }

#pragma unroll
    for (int i = 0; i < 4; i++) {
        long node = base + ng + i;
        if (node < N) {
            ushort4 py, pz;
            py.x = f2h(accL[i][0]); py.y = f2h(accL[i][1]);
            py.z = f2h(accL[i][2]); py.w = f2h(accL[i][3]);
            pz.x = f2h(accR[i][0]); pz.y = f2h(accR[i][1]);
            pz.z = f2h(accR[i][2]); pz.w = f2h(accR[i][3]);
            *(ushort4*)(y + node * D + og) = py;
            *(ushort4*)(z + node * D + og) = pz;
        }
    }
}

// ---------------------------------------------------------------------------
// Degree histogram
// ---------------------------------------------------------------------------
__global__ __launch_bounds__(256) void hist_kernel(
    const int* __restrict__ dst, int* __restrict__ deg, int E)
{
    int e = blockIdx.x * 256 + threadIdx.x;
    if (e < E) atomicAdd(&deg[dst[e]], 1);
}

// ---------------------------------------------------------------------------
// Scan level 1
// ---------------------------------------------------------------------------
__global__ __launch_bounds__(256) void scan1_kernel(
    const int* __restrict__ deg, int* __restrict__ offsets,
    int* __restrict__ blockSums)
{
    __shared__ int s[256];
    int t = threadIdx.x;
    int gid = blockIdx.x * 256 + t;
    int v = deg[gid];
    s[t] = v;
    __syncthreads();
#pragma unroll
    for (int off = 1; off < 256; off <<= 1) {
        int u = (t >= off) ? s[t - off] : 0;
        __syncthreads();
        s[t] += u;
        __syncthreads();
    }
    offsets[gid] = s[t] - v;
    if (t == 255) blockSums[blockIdx.x] = s[t];
}

// ---------------------------------------------------------------------------
// Scan level 2
// ---------------------------------------------------------------------------
__global__ __launch_bounds__(512) void scan2_kernel(
    const int* __restrict__ blockSums, int* __restrict__ blockScanned)
{
    __shared__ int s[512];
    int t = threadIdx.x;
    int v = (t < SCAN_BLOCKS) ? blockSums[t] : 0;
    s[t] = v;
    __syncthreads();
#pragma unroll
    for (int off = 1; off < 512; off <<= 1) {
        int u = (t >= off) ? s[t - off] : 0;
        __syncthreads();
        s[t] += u;
        __syncthreads();
    }
    blockScanned[t] = s[t] - v;
}

// ---------------------------------------------------------------------------
// Scan level 3
// ---------------------------------------------------------------------------
__global__ __launch_bounds__(256) void scan3_kernel(
    int* __restrict__ offsets, const int* __restrict__ blockScanned)
{
    int gid = blockIdx.x * 256 + threadIdx.x;
    offsets[gid] += blockScanned[blockIdx.x];
}

// ---------------------------------------------------------------------------
// Bucket edges into CSR (deg doubles as cursor)
// ---------------------------------------------------------------------------
__global__ __launch_bounds__(256) void bucket_kernel(
    const int* __restrict__ src, const int* __restrict__ dst,
    const int* __restrict__ offsets, int* __restrict__ deg,
    int* __restrict__ csr_src, int E)
{
    int e = blockIdx.x * 256 + threadIdx.x;
    if (e >= E) return;
    int d = dst[e];
    int pos = atomicSub(&deg[d], 1) - 1;
    csr_src[offsets[d] + pos] = src[e];
}

// ---------------------------------------------------------------------------
// Gather + epilogue: out[i] = tanh( sum_{j in N(i)} y[j] + z[i] )
// One wave per node, lane = feature (fp16 rows: 128 B coalesced per wave).
// 4x manual unroll for memory-level parallelism.
// ---------------------------------------------------------------------------
__global__ __launch_bounds__(256) void gather_kernel(
    const ushort_t* __restrict__ y, const ushort_t* __restrict__ z,
    const int* __restrict__ csr_src, const int* __restrict__ offsets,
    float* __restrict__ out, int N)
{
    int node = blockIdx.x * 4 + (threadIdx.x >> 6);
    int lane = threadIdx.x & 63;
    if (node >= N) return;
    int beg = offsets[node];
    int end = offsets[node + 1];

    float acc = 0.0f;
    int i = beg;
    for (; i + 4 <= end; i += 4) {
        int s0 = csr_src[i];
        int s1 = csr_src[i + 1];
        int s2 = csr_src[i + 2];
        int s3 = csr_src[i + 3];
        float v0 = h2f(y[(size_t)s0 * D + lane]);
        float v1 = h2f(y[(size_t)s1 * D + lane]);
        float v2 = h2f(y[(size_t)s2 * D + lane]);
        float v3 = h2f(y[(size_t)s3 * D + lane]);
        acc += (v0 + v1) + (v2 + v3);
    }
    for (; i < end; i++) acc += h2f(y[(size_t)csr_src[i] * D + lane]);

    float o = tanhf(acc + h2f(z[(size_t)node * D + lane]));
    out[(size_t)node * D + lane] = o;
}

extern "C" void kernel_launch(void* const* d_in, const int* in_sizes, int n_in,
                              void* d_out, int out_size, void* d_ws, size_t ws_size,
                              hipStream_t stream) {
    const float* x   = (const float*)d_in[0];
    const int* ei    = (const int*)d_in[1];   // [2,E] int32
    const float* W_l = (const float*)d_in[2];
    const float* b_l = (const float*)d_in[3];
    const float* W_r = (const float*)d_in[4];
    float* out = (float*)d_out;

    const int N = N_NODES;
    const int E = N_EDGES;
    const int* src = ei;
    const int* dst = ei + E;

    // workspace layout (total 31,404,864 B — identical to verified round 2)
    char* ws = (char*)d_ws;
    ushort_t* y        = (ushort_t*)(ws);                      // 12,800,000 B
    ushort_t* z        = (ushort_t*)(ws + 12800000);           // 12,800,000 B
    int* csr_src       = (int*)(ws + 25600000);                //  5,000,000 B
    int* deg           = (int*)(ws + 30600000);                //    400,384 B
    int* offsets       = (int*)(ws + 31000384);                //    400,384 B
    int* blockSums     = (int*)(ws + 31400768);                //      2,048 B
    int* blockScanned  = (int*)(ws + 31402816);                //      2,048 B

    hipMemsetAsync(deg, 0, N_PAD * sizeof(int), stream);

    pre_kernel<<<(N + TN - 1) / TN, 256, 0, stream>>>(x, W_l, b_l, W_r, y, z, N);
    hist_kernel<<<(E + 255) / 256, 256, 0, stream>>>(dst, deg, E);
    scan1_kernel<<<SCAN_BLOCKS, 256, 0, stream>>>(deg, offsets, blockSums);
    scan2_kernel<<<1, 512, 0, stream>>>(blockSums, blockScanned);
    scan3_kernel<<<SCAN_BLOCKS, 256, 0, stream>>>(offsets, blockScanned);
    bucket_kernel<<<(E + 255) / 256, 256, 0, stream>>>(src, dst, offsets, deg, csr_src, E);
    gather_kernel<<<(N + 3) / 4, 256, 0, stream>>>(y, z, csr_src, offsets, out, N);
}